// Round 1
// baseline (572.079 us; speedup 1.0000x reference)
//
#include <hip/hip_runtime.h>

// Problem constants (fixed by setup_inputs)
constexpr int B_  = 8;
constexpr int NI  = 4096;
constexpr int NT  = 512;
constexpr int CD  = 1024;

constexpr int BM  = 64;   // img rows per block
constexpr int BK  = 16;   // K chunk staged in LDS
constexpr int PAD = 4;    // LDS row stride = 20 floats = 80B (16B-aligned, 2-way max aliasing)

// Kernel 1: inv text norms -> d_ws. 4096 rows, one wave per row.
__global__ __launch_bounds__(256) void norms_kernel(const float* __restrict__ text,
                                                    float* __restrict__ inv_norm) {
    int row  = blockIdx.x * 4 + (threadIdx.x >> 6);
    int lane = threadIdx.x & 63;
    const float* p = text + (size_t)row * CD;
    float s = 0.f;
#pragma unroll
    for (int it = 0; it < 4; ++it) {
        int k = (lane + it * 64) * 4;
        float4 v = *reinterpret_cast<const float4*>(p + k);
        s = fmaf(v.x, v.x, s); s = fmaf(v.y, v.y, s);
        s = fmaf(v.z, v.z, s); s = fmaf(v.w, v.w, s);
    }
#pragma unroll
    for (int off = 32; off > 0; off >>= 1) s += __shfl_xor(s, off);
    if (lane == 0) inv_norm[row] = 1.f / fmaxf(sqrtf(s), 1e-12f);
}

// Kernel 2: fused sim-GEMM + argmax + gather.
// Block = 256 threads = 16 tx (text dir) x 16 ty (row dir).
// Thread tile: 4 rows x 32 texts (t = tx + 16j covers all 512 texts).
__global__ __launch_bounds__(256, 2) void align_kernel(const float* __restrict__ img,
                                                       const float* __restrict__ text,
                                                       const float* __restrict__ inv_norm,
                                                       float* __restrict__ out) {
    __shared__ float sA[BM][BK + PAD];
    __shared__ float sB[NT][BK + PAD];
    __shared__ int   s_idx[BM];

    const int tid  = threadIdx.x;
    const int tx   = tid & 15;
    const int ty   = tid >> 4;
    const int b    = blockIdx.y;
    const int row0 = blockIdx.x * BM;

    const int st_t = tid >> 2;         // staging row index base (0..63)
    const int st_k = (tid & 3) * 4;    // staging k offset (0,4,8,12)

    const float* imgBase  = img  + ((size_t)b * NI + row0) * CD;
    const float* textBase = text + (size_t)b * NT * CD;

    // inv norms for this thread's 8 staged text rows (fixed across K chunks)
    float invn[8];
#pragma unroll
    for (int p = 0; p < 8; ++p) invn[p] = inv_norm[b * NT + st_t + p * 64];

    float acc[4][32];
#pragma unroll
    for (int i = 0; i < 4; ++i)
#pragma unroll
        for (int j = 0; j < 32; ++j) acc[i][j] = 0.f;

    for (int kk = 0; kk < CD; kk += BK) {
        __syncthreads();
        // stage A: 64 rows x 16 k (one float4 per thread)
        {
            float4 v = *reinterpret_cast<const float4*>(imgBase + (size_t)st_t * CD + kk + st_k);
            *reinterpret_cast<float4*>(&sA[st_t][st_k]) = v;
        }
        // stage B: 512 rows x 16 k, pre-scaled by inv_norm (8 float4 per thread)
#pragma unroll
        for (int p = 0; p < 8; ++p) {
            int t = st_t + p * 64;
            float4 v = *reinterpret_cast<const float4*>(textBase + (size_t)t * CD + kk + st_k);
            float s = invn[p];
            v.x *= s; v.y *= s; v.z *= s; v.w *= s;
            *reinterpret_cast<float4*>(&sB[t][st_k]) = v;
        }
        __syncthreads();

#pragma unroll 1
        for (int k4 = 0; k4 < BK; k4 += 4) {
            float4 a4[4];
#pragma unroll
            for (int i = 0; i < 4; ++i)
                a4[i] = *reinterpret_cast<const float4*>(&sA[ty * 4 + i][k4]);
#pragma unroll
            for (int j = 0; j < 32; ++j) {
                float4 b4 = *reinterpret_cast<const float4*>(&sB[tx + 16 * j][k4]);
#pragma unroll
                for (int i = 0; i < 4; ++i) {
                    acc[i][j] = fmaf(a4[i].x, b4.x, acc[i][j]);
                    acc[i][j] = fmaf(a4[i].y, b4.y, acc[i][j]);
                    acc[i][j] = fmaf(a4[i].z, b4.z, acc[i][j]);
                    acc[i][j] = fmaf(a4[i].w, b4.w, acc[i][j]);
                }
            }
        }
    }

    // argmax per row: local over 32 j's (t ascending -> first-max kept), then
    // 16-lane shuffle reduce (tie -> lower index, matches np.argmax).
#pragma unroll
    for (int i = 0; i < 4; ++i) {
        float m  = acc[i][0];
        int   mi = tx;
#pragma unroll
        for (int j = 1; j < 32; ++j) {
            int t = tx + 16 * j;
            if (acc[i][j] > m) { m = acc[i][j]; mi = t; }
        }
#pragma unroll
        for (int off = 1; off < 16; off <<= 1) {
            float om = __shfl_xor(m, off);
            int   oi = __shfl_xor(mi, off);
            if (om > m || (om == m && oi < mi)) { m = om; mi = oi; }
        }
        if (tx == 0) s_idx[ty * 4 + i] = mi;
    }
    __syncthreads();

    // gather: out[b][row0+r][:] = text[b][s_idx[r]][:]; fully coalesced float4
    float* outBase = out + ((size_t)b * NI + row0) * CD;
    for (int r = 0; r < BM; ++r) {
        int t = s_idx[r];
        float4 v = *reinterpret_cast<const float4*>(textBase + (size_t)t * CD + tid * 4);
        *reinterpret_cast<float4*>(outBase + (size_t)r * CD + tid * 4) = v;
    }
}

extern "C" void kernel_launch(void* const* d_in, const int* in_sizes, int n_in,
                              void* d_out, int out_size, void* d_ws, size_t ws_size,
                              hipStream_t stream) {
    const float* img  = (const float*)d_in[0];   // [8,4096,1024] fp32
    const float* text = (const float*)d_in[1];   // [8,512,1024] fp32
    float* out      = (float*)d_out;             // [8,4096,1024] fp32
    float* inv_norm = (float*)d_ws;              // 8*512 floats = 16 KB scratch

    norms_kernel<<<dim3(B_ * NT / 4), 256, 0, stream>>>(text, inv_norm);
    align_kernel<<<dim3(NI / BM, B_), 256, 0, stream>>>(img, text, inv_norm, out);
}

// Round 3
// 176.110 us; speedup vs baseline: 3.2484x; 3.2484x over previous
//
#include <hip/hip_runtime.h>

// Problem constants (fixed by setup_inputs)
constexpr int B_  = 8;
constexpr int NI  = 4096;
constexpr int NT  = 512;
constexpr int CD  = 1024;

constexpr int BM    = 128;      // img rows per block
constexpr int BK    = 32;       // K per chunk = one mfma_16x16x32 K-step
constexpr int LDSTR = BK + 8;   // LDS row stride in bf16 elems: 40 -> 80 B
constexpr int MAXC  = 2048;     // candidate list capacity per block
constexpr float DELTA = 4e-3f;  // approx-error margin (~300 sigma of split-bf16 error)

typedef __attribute__((ext_vector_type(4))) float f32x4;
typedef __attribute__((ext_vector_type(8))) short s16x8;

// Kernel 1: inv text norms -> d_ws. One wave per row.
// MUST stay bit-identical to the round-1 version: the refine step reproduces
// round-1 fp32 values (empirically matched np argmax exactly, absmax 0.0).
__global__ __launch_bounds__(256) void norms_kernel(const float* __restrict__ text,
                                                    float* __restrict__ inv_norm) {
    int row  = blockIdx.x * 4 + (threadIdx.x >> 6);
    int lane = threadIdx.x & 63;
    const float* p = text + (size_t)row * CD;
    float s = 0.f;
#pragma unroll
    for (int it = 0; it < 4; ++it) {
        int k = (lane + it * 64) * 4;
        float4 v = *reinterpret_cast<const float4*>(p + k);
        s = fmaf(v.x, v.x, s); s = fmaf(v.y, v.y, s);
        s = fmaf(v.z, v.z, s); s = fmaf(v.w, v.w, s);
    }
#pragma unroll
    for (int off = 32; off > 0; off >>= 1) s += __shfl_xor(s, off);
    if (lane == 0) inv_norm[row] = 1.f / fmaxf(sqrtf(s), 1e-12f);
}

// split x*s into bf16 hi (truncation) + bf16 lo (RN of residual); write both to LDS
__device__ __forceinline__ void split_write(ushort* hDst, ushort* lDst, float4 v, float s) {
    ushort4 h, lo;
#define SPLIT1(c, i)                                                      \
    {                                                                     \
        float xs = v.c * s;                                               \
        unsigned bx = __float_as_uint(xs);                                \
        ((ushort*)&h)[i] = (ushort)(bx >> 16);                            \
        float r = xs - __uint_as_float(bx & 0xFFFF0000u);                 \
        unsigned rb = __float_as_uint(r);                                 \
        rb += 0x7FFFu + ((rb >> 16) & 1u);                                \
        ((ushort*)&lo)[i] = (ushort)(rb >> 16);                           \
    }
    SPLIT1(x, 0) SPLIT1(y, 1) SPLIT1(z, 2) SPLIT1(w, 3)
#undef SPLIT1
    *reinterpret_cast<ushort4*>(hDst) = h;
    *reinterpret_cast<ushort4*>(lDst) = lo;
}

// Kernel 2: split-bf16 MFMA approx sim-GEMM + candidate filter + exact fp32
// refine + gather. 512 threads = 8 waves; wave (wm,wn) owns 64 rows x 128 texts.
__global__ __launch_bounds__(512, 2) void align_kernel(const float* __restrict__ img,
                                                       const float* __restrict__ text,
                                                       const float* __restrict__ inv_norm,
                                                       float* __restrict__ out) {
    __shared__ ushort sAh[BM * LDSTR];           // 10240 B
    __shared__ ushort sAl[BM * LDSTR];           // 10240 B
    __shared__ ushort sBh[NT * LDSTR];           // 40960 B
    __shared__ ushort sBl[NT * LDSTR];           // 40960 B
    __shared__ float  pval[4 * BM];              // per-wn partial max
    __shared__ float  sval[BM];                  // approx row max
    __shared__ unsigned long long keys[BM];      // refined (val,idx) packed
    __shared__ int    cand[MAXC];                // packed (row<<16)|t
    __shared__ int    cnt;
    __shared__ int    sidx[BM];

    const int tid = threadIdx.x;
    const int l   = tid & 63;
    const int w   = tid >> 6;
    const int wm  = w >> 2;        // 0..1 : row half
    const int wn  = w & 3;         // 0..3 : 128-text slice
    const int q   = l >> 4;        // quarter-wave
    const int ln  = l & 15;

    // XCD swizzle: all 32 row-blocks of batch b land on XCD b -> 2MB text
    // panel is L2-resident per XCD.
    const int b    = blockIdx.x & 7;
    const int row0 = (blockIdx.x >> 3) * BM;

    const float* imgBase  = img  + ((size_t)b * NI + row0) * CD;
    const float* textBase = text + (size_t)b * NT * CD;

    // staging map: 8 threads per row (f4 = 16B column), rb = row-within-pass
    const int f4 = tid & 7;
    const int rb = tid >> 3;       // 0..63

    float invn[8];
#pragma unroll
    for (int p = 0; p < 8; ++p) invn[p] = inv_norm[b * NT + p * 64 + rb];

    f32x4 acc[4][8];
#pragma unroll
    for (int mi = 0; mi < 4; ++mi)
#pragma unroll
        for (int nj = 0; nj < 8; ++nj) acc[mi][nj] = (f32x4)0.f;

    // prologue: load chunk 0 into regs
    float4 pa[2], pb[8];
#pragma unroll
    for (int p = 0; p < 2; ++p)
        pa[p] = *reinterpret_cast<const float4*>(imgBase + (size_t)(p * 64 + rb) * CD + f4 * 4);
#pragma unroll
    for (int p = 0; p < 8; ++p)
        pb[p] = *reinterpret_cast<const float4*>(textBase + (size_t)(p * 64 + rb) * CD + f4 * 4);

#pragma unroll 1
    for (int kk = 0; kk < CD; kk += BK) {
        __syncthreads();   // all waves done reading previous chunk's LDS
#pragma unroll
        for (int p = 0; p < 2; ++p) {
            int r = p * 64 + rb;
            split_write(&sAh[r * LDSTR + f4 * 4], &sAl[r * LDSTR + f4 * 4], pa[p], 1.0f);
        }
#pragma unroll
        for (int p = 0; p < 8; ++p) {
            int r = p * 64 + rb;
            split_write(&sBh[r * LDSTR + f4 * 4], &sBl[r * LDSTR + f4 * 4], pb[p], invn[p]);
        }
        __syncthreads();   // chunk staged

        // issue next chunk's global loads (overlap with MFMA phase)
        if (kk + BK < CD) {
            int k2 = kk + BK;
#pragma unroll
            for (int p = 0; p < 2; ++p)
                pa[p] = *reinterpret_cast<const float4*>(imgBase + (size_t)(p * 64 + rb) * CD + k2 + f4 * 4);
#pragma unroll
            for (int p = 0; p < 8; ++p)
                pb[p] = *reinterpret_cast<const float4*>(textBase + (size_t)(p * 64 + rb) * CD + k2 + f4 * 4);
        }

        // compute: 4 M-frags x 8 N-frags x 3 split terms = 96 MFMA
        s16x8 ah[4], al[4];
#pragma unroll
        for (int mi = 0; mi < 4; ++mi) {
            int r = wm * 64 + mi * 16 + ln;
            ah[mi] = *reinterpret_cast<const s16x8*>(&sAh[r * LDSTR + q * 8]);
            al[mi] = *reinterpret_cast<const s16x8*>(&sAl[r * LDSTR + q * 8]);
        }
#pragma unroll
        for (int nj = 0; nj < 8; ++nj) {
            int t = wn * 128 + nj * 16 + ln;
            s16x8 bh = *reinterpret_cast<const s16x8*>(&sBh[t * LDSTR + q * 8]);
            s16x8 bl = *reinterpret_cast<const s16x8*>(&sBl[t * LDSTR + q * 8]);
#pragma unroll
            for (int mi = 0; mi < 4; ++mi) {
                acc[mi][nj] = __builtin_amdgcn_mfma_f32_16x16x32_bf16(ah[mi], bh, acc[mi][nj], 0, 0, 0);
                acc[mi][nj] = __builtin_amdgcn_mfma_f32_16x16x32_bf16(al[mi], bh, acc[mi][nj], 0, 0, 0);
                acc[mi][nj] = __builtin_amdgcn_mfma_f32_16x16x32_bf16(ah[mi], bl, acc[mi][nj], 0, 0, 0);
            }
        }
    }

    // --- per-wave approx max per row (value only; indices resolved in refine) ---
    // C/D layout: col = ln (text), row = q*4 + r  [m89]
#pragma unroll
    for (int mi = 0; mi < 4; ++mi) {
#pragma unroll
        for (int r = 0; r < 4; ++r) {
            float m = acc[mi][0][r];
#pragma unroll
            for (int nj = 1; nj < 8; ++nj) m = fmaxf(m, acc[mi][nj][r]);
#pragma unroll
            for (int off = 1; off < 16; off <<= 1) m = fmaxf(m, __shfl_xor(m, off));
            if (ln == 0) pval[wn * BM + (wm * 64 + mi * 16 + q * 4 + r)] = m;
        }
    }
    __syncthreads();

    // --- merge 4 wn-slices -> row max; init refine state ---
    if (tid < BM) {
        float bv = pval[tid];
#pragma unroll
        for (int ww = 1; ww < 4; ++ww) bv = fmaxf(bv, pval[ww * BM + tid]);
        sval[tid] = bv;
        keys[tid] = 0ull;
    }
    if (tid == 0) cnt = 0;
    __syncthreads();

    // --- candidate collection: all (row,t) with approx >= rowmax - DELTA ---
    {
        float thr[4][4];
#pragma unroll
        for (int mi = 0; mi < 4; ++mi)
#pragma unroll
            for (int r = 0; r < 4; ++r)
                thr[mi][r] = sval[wm * 64 + mi * 16 + q * 4 + r] - DELTA;
#pragma unroll
        for (int mi = 0; mi < 4; ++mi)
#pragma unroll
            for (int nj = 0; nj < 8; ++nj)
#pragma unroll
                for (int r = 0; r < 4; ++r) {
                    if (acc[mi][nj][r] >= thr[mi][r]) {
                        int rl = wm * 64 + mi * 16 + q * 4 + r;
                        int t  = wn * 128 + nj * 16 + ln;
                        int slot = atomicAdd(&cnt, 1);
                        if (slot < MAXC) cand[slot] = (rl << 16) | t;
                    }
                }
    }
    __syncthreads();

    // --- exact fp32 refine: replicate round-1 arithmetic (ascending-k fmaf
    // chain, text element scaled by invn with one fp32 mul) ---
    {
        int n = cnt < MAXC ? cnt : MAXC;
        for (int c = tid; c < n; c += 512) {
            int rt = cand[c];
            int rl = rt >> 16;
            int t  = rt & 0xFFFF;
            const float* ap = imgBase  + (size_t)rl * CD;
            const float* bp = textBase + (size_t)t  * CD;
            float s = inv_norm[b * NT + t];
            float accv = 0.f;
#pragma unroll 2
            for (int k = 0; k < CD; k += 4) {
                float4 av = *reinterpret_cast<const float4*>(ap + k);
                float4 bv = *reinterpret_cast<const float4*>(bp + k);
                accv = fmaf(av.x, bv.x * s, accv);
                accv = fmaf(av.y, bv.y * s, accv);
                accv = fmaf(av.z, bv.z * s, accv);
                accv = fmaf(av.w, bv.w * s, accv);
            }
            // sortable-uint encode; tie (equal value) -> lower t wins
            unsigned ub = __float_as_uint(accv);
            unsigned su = ub ^ ((unsigned)((int)ub >> 31) | 0x80000000u);
            unsigned long long key =
                ((unsigned long long)su << 32) | (unsigned)(NT - 1 - t);
            atomicMax(&keys[rl], key);
        }
    }
    __syncthreads();

    if (tid < BM) sidx[tid] = NT - 1 - (int)(keys[tid] & 0xFFFFFFFFull);
    __syncthreads();

    // --- gather: wave w copies rows w*16 .. w*16+15, coalesced float4 ---
    float* outBase = out + ((size_t)b * NI + row0) * CD;
#pragma unroll 1
    for (int rr = 0; rr < 16; ++rr) {
        int row = w * 16 + rr;
        int ti  = sidx[row];
        const float4* src = reinterpret_cast<const float4*>(textBase + (size_t)ti * CD);
        float4*       dst = reinterpret_cast<float4*>(outBase + (size_t)row * CD);
#pragma unroll
        for (int i = 0; i < 4; ++i) dst[l + 64 * i] = src[l + 64 * i];
    }
}

extern "C" void kernel_launch(void* const* d_in, const int* in_sizes, int n_in,
                              void* d_out, int out_size, void* d_ws, size_t ws_size,
                              hipStream_t stream) {
    const float* img  = (const float*)d_in[0];   // [8,4096,1024] fp32
    const float* text = (const float*)d_in[1];   // [8,512,1024] fp32
    float* out      = (float*)d_out;             // [8,4096,1024] fp32
    float* inv_norm = (float*)d_ws;              // 8*512 floats = 16 KB scratch

    norms_kernel<<<dim3(B_ * NT / 4), 256, 0, stream>>>(text, inv_norm);
    align_kernel<<<dim3(NI / BM * B_), 512, 0, stream>>>(img, text, inv_norm, out);
}

// Round 4
// 160.321 us; speedup vs baseline: 3.5683x; 1.0985x over previous
//
#include <hip/hip_runtime.h>

// Problem constants (fixed by setup_inputs)
constexpr int B_  = 8;
constexpr int NI  = 4096;
constexpr int NT  = 512;
constexpr int CD  = 1024;

constexpr int BM   = 128;       // img rows per block
constexpr int BK   = 32;        // K per chunk = one mfma_16x16x32 K-step
constexpr int NCH  = CD / BK;   // 32 chunks
constexpr int MAXC = 1024;      // candidate list capacity per block
constexpr float DELTA = 0.02f;  // filter margin (~50 sigma of fp16 approx error; top-2 gap ~0.32)

typedef __attribute__((ext_vector_type(4))) float    f32x4;
typedef __attribute__((ext_vector_type(8))) _Float16 f16x8;

// Kernel 1: inv text norms (bit-identical reduce to R1 — refine replicates R1
// values which empirically matched np argmax, absmax 0.0) + optional pre-scaled
// fp16 text panel in chunk-major layout ws[b][kc][t][32].
template<bool PRE>
__global__ __launch_bounds__(256) void prep_kernel(const float* __restrict__ text,
                                                   float* __restrict__ inv_norm,
                                                   _Float16* __restrict__ wsB) {
    int row  = blockIdx.x * 4 + (threadIdx.x >> 6);
    int lane = threadIdx.x & 63;
    const float* p = text + (size_t)row * CD;
    float s = 0.f;
#pragma unroll
    for (int it = 0; it < 4; ++it) {
        int k = (lane + it * 64) * 4;
        float4 v = *reinterpret_cast<const float4*>(p + k);
        s = fmaf(v.x, v.x, s); s = fmaf(v.y, v.y, s);
        s = fmaf(v.z, v.z, s); s = fmaf(v.w, v.w, s);
    }
#pragma unroll
    for (int off = 32; off > 0; off >>= 1) s += __shfl_xor(s, off);
    float inv = 1.f / fmaxf(sqrtf(s), 1e-12f);
    if (lane == 0) inv_norm[row] = inv;

    if (PRE) {
        // lane l owns elems k = l*16 .. l*16+15 -> chunk kc = l>>1, half = l&1
        int b = row >> 9, t = row & 511;
        int kc = lane >> 1, half = lane & 1;
        _Float16* dst = wsB + (((size_t)b * 32 + kc) * 512 + t) * 32 + half * 16;
        const float* src = p + lane * 16;
        f16x8 h0, h1;
#pragma unroll
        for (int j = 0; j < 2; ++j) {
            float4 v = *reinterpret_cast<const float4*>(src + j * 4);
            h0[j * 4 + 0] = (_Float16)(v.x * inv); h0[j * 4 + 1] = (_Float16)(v.y * inv);
            h0[j * 4 + 2] = (_Float16)(v.z * inv); h0[j * 4 + 3] = (_Float16)(v.w * inv);
        }
#pragma unroll
        for (int j = 0; j < 2; ++j) {
            float4 v = *reinterpret_cast<const float4*>(src + 8 + j * 4);
            h1[j * 4 + 0] = (_Float16)(v.x * inv); h1[j * 4 + 1] = (_Float16)(v.y * inv);
            h1[j * 4 + 2] = (_Float16)(v.z * inv); h1[j * 4 + 3] = (_Float16)(v.w * inv);
        }
        *reinterpret_cast<f16x8*>(dst)     = h0;
        *reinterpret_cast<f16x8*>(dst + 8) = h1;
    }
}

// Kernel 2: LDS-free fp16 MFMA approx sim-GEMM (no barriers in K loop) +
// candidate filter + exact fp32 refine (only rows with >=2 candidates) + gather.
// 512 threads = 8 waves; wave (wm = w>>2, wn = w&3) owns 64 rows x 128 texts.
template<bool PRE>
__global__ __launch_bounds__(512, 2) void align_kernel(const float* __restrict__ img,
                                                       const float* __restrict__ text,
                                                       const float* __restrict__ inv_norm,
                                                       const _Float16* __restrict__ wsB,
                                                       float* __restrict__ out) {
    __shared__ float pval[4 * BM];
    __shared__ int   pidx[4 * BM];
    __shared__ float sval[BM];
    __shared__ int   sidx[BM];
    __shared__ int   rowcnt[BM];
    __shared__ unsigned long long keys[BM];
    __shared__ int   cand[MAXC];
    __shared__ int   cnt;

    const int tid = threadIdx.x;
    const int l   = tid & 63;
    const int w   = tid >> 6;
    const int wm  = w >> 2;        // 0..1 : row half
    const int wn  = w & 3;         // 0..3 : 128-text slice
    const int q   = l >> 4;        // quarter-wave -> k-slice q*8
    const int ln  = l & 15;

    // XCD swizzle: blockIdx%8 ~ XCD id -> each XCD serves one batch's text panel from L2
    const int b    = blockIdx.x & 7;
    const int row0 = (blockIdx.x >> 3) * BM;

    const float* imgBase  = img  + ((size_t)b * NI + row0) * CD;
    const float* textBase = text + (size_t)b * NT * CD;

    // A fragment pointers: row = row0 + wm*64 + mi*16 + ln, k base = q*8
    const float* aPtr[4];
#pragma unroll
    for (int mi = 0; mi < 4; ++mi)
        aPtr[mi] = imgBase + (size_t)(wm * 64 + mi * 16 + ln) * CD + q * 8;

    // B fragment pointers
    const _Float16* bPtr[8];   // PRE path: ws chunk-major
    const float*    bPtrF[8];  // fallback: fp32 text
    float invn8[8];
#pragma unroll
    for (int nj = 0; nj < 8; ++nj) {
        int t = wn * 128 + nj * 16 + ln;
        if (PRE) {
            bPtr[nj] = wsB + ((size_t)b * 32 * 512 + t) * 32 + q * 8;
        } else {
            bPtrF[nj] = textBase + (size_t)t * CD + q * 8;
            invn8[nj] = inv_norm[b * NT + t];
        }
    }

    f32x4 acc[4][8];
#pragma unroll
    for (int mi = 0; mi < 4; ++mi)
#pragma unroll
        for (int nj = 0; nj < 8; ++nj) acc[mi][nj] = (f32x4)0.f;

    // prologue: A chunk 0
    float4 a0[4], a1[4];
#pragma unroll
    for (int mi = 0; mi < 4; ++mi) {
        a0[mi] = *reinterpret_cast<const float4*>(aPtr[mi]);
        a1[mi] = *reinterpret_cast<const float4*>(aPtr[mi] + 4);
    }

#pragma unroll 1
    for (int kc = 0; kc < NCH; ++kc) {
        // B loads for this chunk (L2-hot)
        f16x8 bf[8];
        if (PRE) {
#pragma unroll
            for (int nj = 0; nj < 8; ++nj)
                bf[nj] = *reinterpret_cast<const f16x8*>(bPtr[nj] + (size_t)kc * 16384);
        } else {
#pragma unroll
            for (int nj = 0; nj < 8; ++nj) {
                float4 v0 = *reinterpret_cast<const float4*>(bPtrF[nj] + kc * BK);
                float4 v1 = *reinterpret_cast<const float4*>(bPtrF[nj] + kc * BK + 4);
                float sj = invn8[nj];
                f16x8 t;
                t[0] = (_Float16)(v0.x * sj); t[1] = (_Float16)(v0.y * sj);
                t[2] = (_Float16)(v0.z * sj); t[3] = (_Float16)(v0.w * sj);
                t[4] = (_Float16)(v1.x * sj); t[5] = (_Float16)(v1.y * sj);
                t[6] = (_Float16)(v1.z * sj); t[7] = (_Float16)(v1.w * sj);
                bf[nj] = t;
            }
        }

        // convert A chunk (waits on prefetched loads)
        f16x8 af[4];
#pragma unroll
        for (int mi = 0; mi < 4; ++mi) {
            f16x8 t;
            t[0] = (_Float16)a0[mi].x; t[1] = (_Float16)a0[mi].y;
            t[2] = (_Float16)a0[mi].z; t[3] = (_Float16)a0[mi].w;
            t[4] = (_Float16)a1[mi].x; t[5] = (_Float16)a1[mi].y;
            t[6] = (_Float16)a1[mi].z; t[7] = (_Float16)a1[mi].w;
            af[mi] = t;
        }

        // prefetch next A chunk (lands during MFMA phase)
        if (kc + 1 < NCH) {
#pragma unroll
            for (int mi = 0; mi < 4; ++mi) {
                a0[mi] = *reinterpret_cast<const float4*>(aPtr[mi] + (kc + 1) * BK);
                a1[mi] = *reinterpret_cast<const float4*>(aPtr[mi] + (kc + 1) * BK + 4);
            }
        }

        // 32 MFMA
#pragma unroll
        for (int nj = 0; nj < 8; ++nj)
#pragma unroll
            for (int mi = 0; mi < 4; ++mi)
                acc[mi][nj] = __builtin_amdgcn_mfma_f32_16x16x32_f16(af[mi], bf[nj], acc[mi][nj], 0, 0, 0);
    }

    // --- approx argmax per row WITH index (first-occurrence tie rule) ---
    // C/D layout: col = ln (text), row = q*4 + r  [m89]
#pragma unroll
    for (int mi = 0; mi < 4; ++mi) {
#pragma unroll
        for (int r = 0; r < 4; ++r) {
            float m  = acc[mi][0][r];
            int   bi = wn * 128 + ln;
#pragma unroll
            for (int nj = 1; nj < 8; ++nj) {
                float v = acc[mi][nj][r];
                int  ci = wn * 128 + nj * 16 + ln;
                if (v > m) { m = v; bi = ci; }
            }
#pragma unroll
            for (int off = 1; off < 16; off <<= 1) {
                float om = __shfl_xor(m, off);
                int   oi = __shfl_xor(bi, off);
                if (om > m || (om == m && oi < bi)) { m = om; bi = oi; }
            }
            if (ln == 0) {
                int rl = wm * 64 + mi * 16 + q * 4 + r;
                pval[wn * BM + rl] = m;
                pidx[wn * BM + rl] = bi;
            }
        }
    }
    __syncthreads();

    // --- merge 4 wn-slices (ascending wn = ascending col -> first-occurrence) ---
    if (tid < BM) {
        float bv = pval[tid];
        int   bi = pidx[tid];
#pragma unroll
        for (int ww = 1; ww < 4; ++ww) {
            float v  = pval[ww * BM + tid];
            int   i2 = pidx[ww * BM + tid];
            if (v > bv || (v == bv && i2 < bi)) { bv = v; bi = i2; }
        }
        sval[tid]   = bv;
        sidx[tid]   = bi;    // provisional answer (exact if rowcnt==1)
        rowcnt[tid] = 0;
        keys[tid]   = 0ull;
    }
    if (tid == 0) cnt = 0;
    __syncthreads();

    // --- candidate collection: all (row,t) with approx >= rowmax - DELTA ---
    {
        float thr[4][4];
#pragma unroll
        for (int mi = 0; mi < 4; ++mi)
#pragma unroll
            for (int r = 0; r < 4; ++r)
                thr[mi][r] = sval[wm * 64 + mi * 16 + q * 4 + r] - DELTA;
#pragma unroll
        for (int mi = 0; mi < 4; ++mi)
#pragma unroll
            for (int nj = 0; nj < 8; ++nj)
#pragma unroll
                for (int r = 0; r < 4; ++r) {
                    if (acc[mi][nj][r] >= thr[mi][r]) {
                        int rl = wm * 64 + mi * 16 + q * 4 + r;
                        int t  = wn * 128 + nj * 16 + ln;
                        atomicAdd(&rowcnt[rl], 1);
                        int slot = atomicAdd(&cnt, 1);
                        if (slot < MAXC) cand[slot] = (rl << 16) | t;
                    }
                }
    }
    __syncthreads();

    // --- exact fp32 refine, only rows with >=2 candidates (~3% of rows).
    // Replicates R1 arithmetic exactly (ascending-k fmaf chain, text elem
    // scaled by inv_norm with one fp32 mul) -> matches np argmax as proven R3.
    {
        int n = cnt < MAXC ? cnt : MAXC;
        for (int c = tid; c < n; c += 512) {
            int rt = cand[c];
            int rl = rt >> 16;
            int t  = rt & 0xFFFF;
            if (rowcnt[rl] < 2) continue;
            const float* ap = imgBase  + (size_t)rl * CD;
            const float* bp = textBase + (size_t)t  * CD;
            float s = inv_norm[b * NT + t];
            float accv = 0.f;
#pragma unroll 2
            for (int k = 0; k < CD; k += 4) {
                float4 av = *reinterpret_cast<const float4*>(ap + k);
                float4 bv = *reinterpret_cast<const float4*>(bp + k);
                accv = fmaf(av.x, bv.x * s, accv);
                accv = fmaf(av.y, bv.y * s, accv);
                accv = fmaf(av.z, bv.z * s, accv);
                accv = fmaf(av.w, bv.w * s, accv);
            }
            unsigned ub = __float_as_uint(accv);
            unsigned su = ub ^ ((unsigned)((int)ub >> 31) | 0x80000000u);
            unsigned long long key =
                ((unsigned long long)su << 32) | (unsigned)(NT - 1 - t);
            atomicMax(&keys[rl], key);
        }
    }
    __syncthreads();

    if (tid < BM && rowcnt[tid] > 1)
        sidx[tid] = NT - 1 - (int)(keys[tid] & 0xFFFFFFFFull);
    __syncthreads();

    // --- gather: wave w copies rows w*16 .. w*16+15, coalesced float4 ---
    float* outBase = out + ((size_t)b * NI + row0) * CD;
#pragma unroll 1
    for (int rr = 0; rr < 16; ++rr) {
        int row = w * 16 + rr;
        int ti  = sidx[row];
        const float4* src = reinterpret_cast<const float4*>(textBase + (size_t)ti * CD);
        float4*       dst = reinterpret_cast<float4*>(outBase + (size_t)row * CD);
#pragma unroll
        for (int i = 0; i < 4; ++i) dst[l + 64 * i] = src[l + 64 * i];
    }
}

extern "C" void kernel_launch(void* const* d_in, const int* in_sizes, int n_in,
                              void* d_out, int out_size, void* d_ws, size_t ws_size,
                              hipStream_t stream) {
    const float* img  = (const float*)d_in[0];   // [8,4096,1024] fp32
    const float* text = (const float*)d_in[1];   // [8,512,1024] fp32
    float* out      = (float*)d_out;             // [8,4096,1024] fp32
    float* inv_norm = (float*)d_ws;              // 4096 floats
    _Float16* wsB   = (_Float16*)((char*)d_ws + 16384);

    size_t need = 16384 + (size_t)B_ * NT * CD * sizeof(_Float16);  // 8.4 MB
    if (ws_size >= need) {
        prep_kernel<true><<<dim3(B_ * NT / 4), 256, 0, stream>>>(text, inv_norm, wsB);
        align_kernel<true><<<dim3(NI / BM * B_), 512, 0, stream>>>(img, text, inv_norm, wsB, out);
    } else {
        prep_kernel<false><<<dim3(B_ * NT / 4), 256, 0, stream>>>(text, inv_norm, wsB);
        align_kernel<false><<<dim3(NI / BM * B_), 512, 0, stream>>>(img, text, inv_norm, wsB, out);
    }
}